// Round 6
// baseline (2455.989 us; speedup 1.0000x reference)
//
#include <hip/hip_runtime.h>

#define E 16
#define HID 32
#define NSTEP 10
#define TAU 0.5f
#define SIGMA 0.5f
#define RES 0.5f
#define P 2   // points per thread: weight scalars fetched once, used P times

__device__ __forceinline__ float fast_tanh(float v) {
    float e = __expf(2.0f * v);
    return 1.0f - __fdividef(2.0f, e + 1.0f);
}
// scale = 1/max(sqrt(n2),1) == min(rsq(n2), 1)   (n2=0 -> rsq=inf -> min -> 1)
__device__ __forceinline__ float inv_norm_clamped(float n2) {
    return fminf(__builtin_amdgcn_rsqf(n2), 1.0f);
}

// waves_per_eu(4,4): 128-VGPR budget. R3 ran VGPR=64 with ~100 live values ->
// allocator rematerialized per-step (VALU bloat). R4/R5 lesson: f16 inside the
// 10-step feedback loop fails numerics (error gain ~50-100x) -> pure f32.
// Wp2 (512 floats) is the one weight block that can't sit in the 102-SGPR file;
// it gets a dedicated LDS broadcast path (2KB, uniform-address float4 reads).
__global__ __attribute__((amdgpu_waves_per_eu(4, 4))) __launch_bounds__(256)
void pdhg_kernel(
    const float* __restrict__ xg,  const float* __restrict__ Gg,  const float* __restrict__ hg,
    const float* __restrict__ W1,  const float* __restrict__ b1,
    const float* __restrict__ W2,  const float* __restrict__ b2,
    const float* __restrict__ Wmu, const float* __restrict__ bmu,
    const float* __restrict__ Wy,  const float* __restrict__ by,
    const float* __restrict__ Wp1, const float* __restrict__ bp1,
    const float* __restrict__ Wp2, const float* __restrict__ bp2,
    float* __restrict__ out, int npts)
{
    // ---- LDS: Wp2 only (row-major [k][E], 512 floats = 2KB) ----
    __shared__ __align__(16) float sWp2[HID * E];
    {
        const int tid = threadIdx.x;
        for (int i = tid; i < HID * E; i += 256) sWp2[i] = Wp2[i];
    }
    __syncthreads();

    const int half = (npts + 1) >> 1;
    const int t = blockIdx.x * blockDim.x + threadIdx.x;
    if (t >= half) return;

    const int i1 = t + half;
    const bool live1 = (i1 < npts);
    const int i1c = live1 ? i1 : t;   // clamped: harmless duplicate compute on odd tails

    float x0[P], x1[P];
    {
        const float2 a0 = reinterpret_cast<const float2*>(xg)[t];
        const float2 a1 = reinterpret_cast<const float2*>(xg)[i1c];
        x0[0] = a0.x; x1[0] = a0.y;
        x0[1] = a1.x; x1[1] = a1.y;
    }

    // ---------------- encoder: fused L1+L2, f in chunks of 8 (pressure cap) ----
    // g = relu( relu(x@W1+b1) @ W2 + b2 ); i-ascending accumulation == R0 rounding
    float g[P][HID];
    #pragma unroll
    for (int j = 0; j < HID; ++j) {
        const float bb = b2[j];
        #pragma unroll
        for (int p = 0; p < P; ++p) g[p][j] = bb;
    }
    #pragma unroll
    for (int ci = 0; ci < 4; ++ci) {
        float fc[P][8];
        #pragma unroll
        for (int jj = 0; jj < 8; ++jj) {
            const int j = ci * 8 + jj;
            const float w0 = W1[j], w1 = W1[HID + j], bb = b1[j];
            #pragma unroll
            for (int p = 0; p < P; ++p)
                fc[p][jj] = fmaxf(fmaf(x0[p], w0, fmaf(x1[p], w1, bb)), 0.0f);
        }
        #pragma unroll
        for (int ii = 0; ii < 8; ++ii) {
            const int i = ci * 8 + ii;
            #pragma unroll
            for (int j = 0; j < HID; ++j) {
                const float w = W2[i * HID + j];
                #pragma unroll
                for (int p = 0; p < P; ++p) g[p][j] = fmaf(fc[p][ii], w, g[p][j]);
            }
        }
    }
    #pragma unroll
    for (int j = 0; j < HID; ++j)
        #pragma unroll
        for (int p = 0; p < P; ++p) g[p][j] = fmaxf(g[p][j], 0.0f);

    // ---------------- heads: mu = relu(g@Wmu+bmu), y = tanh(g@Wy+by) ----------
    float mu[P][E];
    #pragma unroll
    for (int e = 0; e < E; ++e) {
        const float bb = bmu[e];
        #pragma unroll
        for (int p = 0; p < P; ++p) mu[p][e] = bb;
    }
    float y0[P], y1[P];
    {
        const float b0 = by[0], b1v = by[1];
        #pragma unroll
        for (int p = 0; p < P; ++p) { y0[p] = b0; y1[p] = b1v; }
    }
    #pragma unroll
    for (int j = 0; j < HID; ++j) {
        #pragma unroll
        for (int e = 0; e < E; ++e) {
            const float w = Wmu[j * E + e];
            #pragma unroll
            for (int p = 0; p < P; ++p) mu[p][e] = fmaf(g[p][j], w, mu[p][e]);
        }
        const float wy0 = Wy[j * 2], wy1 = Wy[j * 2 + 1];
        #pragma unroll
        for (int p = 0; p < P; ++p) {
            y0[p] = fmaf(g[p][j], wy0, y0[p]);
            y1[p] = fmaf(g[p][j], wy1, y1[p]);
        }
    }
    #pragma unroll
    for (int e = 0; e < E; ++e)
        #pragma unroll
        for (int p = 0; p < P; ++p) mu[p][e] = fmaxf(mu[p][e], 0.0f);
    #pragma unroll
    for (int p = 0; p < P; ++p) { y0[p] = fast_tanh(y0[p]); y1[p] = fast_tanh(y1[p]); }
    // g dead from here

    // ------- ta = TAU*(x@G^T - h) ; tc = TAU*(a@G) ; tg = TAU*GtG ; v = mu@G -------
    float ta[P][E];
    float tc0[P], tc1[P], v0[P], v1[P];
    float g00 = 0.f, g01 = 0.f, g11 = 0.f;
    #pragma unroll
    for (int p = 0; p < P; ++p) { tc0[p] = 0.f; tc1[p] = 0.f; v0[p] = 0.f; v1[p] = 0.f; }
    #pragma unroll
    for (int e = 0; e < E; ++e) {
        const float gx = Gg[2 * e], gy = Gg[2 * e + 1], he = hg[e];
        g00 = fmaf(gx, gx, g00);
        g01 = fmaf(gx, gy, g01);
        g11 = fmaf(gy, gy, g11);
        #pragma unroll
        for (int p = 0; p < P; ++p) {
            const float ae = fmaf(x0[p], gx, fmaf(x1[p], gy, -he));
            const float tae = TAU * ae;
            ta[p][e] = tae;
            tc0[p] = fmaf(tae, gx, tc0[p]);
            tc1[p] = fmaf(tae, gy, tc1[p]);
            v0[p] = fmaf(mu[p][e], gx, v0[p]);
            v1[p] = fmaf(mu[p][e], gy, v1[p]);
        }
    }
    const float tg00 = TAU * g00, tg01 = TAU * g01, tg11 = TAU * g11;
    // x dead from here

    // ---------------- PDHG steps ----------------
    #pragma unroll 1
    for (int s = 0; s < NSTEP; ++s) {
        float z0[P], z1[P], yt0[P], yt1[P];
        #pragma unroll
        for (int p = 0; p < P; ++p) {
            // y += SIGMA*v; unit-ball project
            y0[p] = fmaf(SIGMA, v0[p], y0[p]);
            y1[p] = fmaf(SIGMA, v1[p], y1[p]);
            const float sc = inv_norm_clamped(fmaf(y0[p], y0[p], y1[p] * y1[p]));
            y0[p] *= sc; y1[p] *= sc;
            // z = mu'@G without the dot: z = v + TAU*c - TAU*GtG@y
            z0[p] = fmaf(-tg00, y0[p], fmaf(-tg01, y1[p], v0[p] + tc0[p]));
            z1[p] = fmaf(-tg01, y0[p], fmaf(-tg11, y1[p], v1[p] + tc1[p]));
            yt0[p] = TAU * y0[p]; yt1[p] = TAU * y1[p];
        }

        // mu += TAU*(a - y@G^T) == mu + ta - yt0*gx - yt1*gy
        #pragma unroll
        for (int e = 0; e < E; ++e) {
            const float gx = Gg[2 * e], gy = Gg[2 * e + 1];
            #pragma unroll
            for (int p = 0; p < P; ++p)
                mu[p][e] = fmaf(-yt1[p], gy, fmaf(-yt0[p], gx, mu[p][e] + ta[p][e]));
        }

        // fused prox head: hidden value produced & immediately consumed.
        // Wp2 row k arrives via LDS broadcast (uniform addr, imm offsets) --
        // 4 ds_read_b128 per 32 FMAs, zero SGPR pressure.
        float dl[P][E];
        #pragma unroll
        for (int e = 0; e < E; ++e) {
            const float bb = bp2[e];
            #pragma unroll
            for (int p = 0; p < P; ++p) dl[p][e] = bb;
        }
        #pragma unroll
        for (int k = 0; k < HID; ++k) {
            const float wa = Wp1[k], wb = Wp1[HID + k], bb = bp1[k];
            float hk[P];
            #pragma unroll
            for (int p = 0; p < P; ++p)
                hk[p] = fmaxf(fmaf(z0[p], wa, fmaf(z1[p], wb, bb)), 0.0f);
            const float4* row = reinterpret_cast<const float4*>(sWp2 + k * E);
            {
                const float4 w0 = row[0], w1 = row[1];
                #pragma unroll
                for (int p = 0; p < P; ++p) {
                    dl[p][0] = fmaf(hk[p], w0.x, dl[p][0]);
                    dl[p][1] = fmaf(hk[p], w0.y, dl[p][1]);
                    dl[p][2] = fmaf(hk[p], w0.z, dl[p][2]);
                    dl[p][3] = fmaf(hk[p], w0.w, dl[p][3]);
                    dl[p][4] = fmaf(hk[p], w1.x, dl[p][4]);
                    dl[p][5] = fmaf(hk[p], w1.y, dl[p][5]);
                    dl[p][6] = fmaf(hk[p], w1.z, dl[p][6]);
                    dl[p][7] = fmaf(hk[p], w1.w, dl[p][7]);
                }
            }
            {
                const float4 w2 = row[2], w3 = row[3];
                #pragma unroll
                for (int p = 0; p < P; ++p) {
                    dl[p][8]  = fmaf(hk[p], w2.x, dl[p][8]);
                    dl[p][9]  = fmaf(hk[p], w2.y, dl[p][9]);
                    dl[p][10] = fmaf(hk[p], w2.z, dl[p][10]);
                    dl[p][11] = fmaf(hk[p], w2.w, dl[p][11]);
                    dl[p][12] = fmaf(hk[p], w3.x, dl[p][12]);
                    dl[p][13] = fmaf(hk[p], w3.y, dl[p][13]);
                    dl[p][14] = fmaf(hk[p], w3.z, dl[p][14]);
                    dl[p][15] = fmaf(hk[p], w3.w, dl[p][15]);
                }
            }
        }

        // mu = project_mu(mu + RES*dl); maintain v = sc * (pre-scale mu@G)
        float p0a[P], p1a[P];
        #pragma unroll
        for (int p = 0; p < P; ++p) { p0a[p] = 0.f; p1a[p] = 0.f; }
        #pragma unroll
        for (int e = 0; e < E; ++e) {
            const float gx = Gg[2 * e], gy = Gg[2 * e + 1];
            #pragma unroll
            for (int p = 0; p < P; ++p) {
                const float m = fmaxf(fmaf(RES, dl[p][e], mu[p][e]), 0.0f);
                mu[p][e] = m;
                p0a[p] = fmaf(m, gx, p0a[p]);
                p1a[p] = fmaf(m, gy, p1a[p]);
            }
        }
        #pragma unroll
        for (int p = 0; p < P; ++p) {
            const float sc = inv_norm_clamped(fmaf(p0a[p], p0a[p], p1a[p] * p1a[p]));
            #pragma unroll
            for (int e = 0; e < E; ++e) mu[p][e] *= sc;
            v0[p] = sc * p0a[p];
            v1[p] = sc * p1a[p];
        }
    }

    // final project_mu is the identity here: mu >= 0 and ||mu@G|| <= 1 already.

    // ---------------- store 16 contiguous floats per point ----------------
    {
        float4* o = reinterpret_cast<float4*>(out + (size_t)t * E);
        o[0] = make_float4(mu[0][0],  mu[0][1],  mu[0][2],  mu[0][3]);
        o[1] = make_float4(mu[0][4],  mu[0][5],  mu[0][6],  mu[0][7]);
        o[2] = make_float4(mu[0][8],  mu[0][9],  mu[0][10], mu[0][11]);
        o[3] = make_float4(mu[0][12], mu[0][13], mu[0][14], mu[0][15]);
    }
    if (live1) {
        float4* o = reinterpret_cast<float4*>(out + (size_t)i1 * E);
        o[0] = make_float4(mu[1][0],  mu[1][1],  mu[1][2],  mu[1][3]);
        o[1] = make_float4(mu[1][4],  mu[1][5],  mu[1][6],  mu[1][7]);
        o[2] = make_float4(mu[1][8],  mu[1][9],  mu[1][10], mu[1][11]);
        o[3] = make_float4(mu[1][12], mu[1][13], mu[1][14], mu[1][15]);
    }
}

extern "C" void kernel_launch(void* const* d_in, const int* in_sizes, int n_in,
                              void* d_out, int out_size, void* d_ws, size_t ws_size,
                              hipStream_t stream) {
    const float* x   = (const float*)d_in[0];
    const float* G   = (const float*)d_in[1];
    const float* h   = (const float*)d_in[2];
    const float* W1  = (const float*)d_in[3];
    const float* b1  = (const float*)d_in[4];
    const float* W2  = (const float*)d_in[5];
    const float* b2  = (const float*)d_in[6];
    const float* Wmu = (const float*)d_in[7];
    const float* bmu = (const float*)d_in[8];
    const float* Wy  = (const float*)d_in[9];
    const float* by  = (const float*)d_in[10];
    const float* Wp1 = (const float*)d_in[11];
    const float* bp1 = (const float*)d_in[12];
    const float* Wp2 = (const float*)d_in[13];
    const float* bp2 = (const float*)d_in[14];

    const int npts = in_sizes[0] / 2;   // x is [N,2]
    const int half = (npts + 1) >> 1;   // P=2 points per thread
    const int block = 256;
    const int grid = (half + block - 1) / block;

    pdhg_kernel<<<grid, block, 0, stream>>>(x, G, h, W1, b1, W2, b2, Wmu, bmu,
                                            Wy, by, Wp1, bp1, Wp2, bp2,
                                            (float*)d_out, npts);
}

// Round 7
// 247.211 us; speedup vs baseline: 9.9348x; 9.9348x over previous
//
#include <hip/hip_runtime.h>

#define E 16
#define HID 32
#define NSTEP 10
#define TAU 0.5f
#define SIGMA 0.5f
#define RES 0.5f
#define NT 4          // 16-point column tiles per wave (64 pts/wave)
#define STRIDE 36     // LDS row stride (floats): 144B, 16B-aligned

typedef __attribute__((ext_vector_type(8))) short bf16x8;
typedef __attribute__((ext_vector_type(4))) float f32x4;
typedef __attribute__((ext_vector_type(4))) unsigned int u32x4;

__device__ __forceinline__ f32x4 mfma16(bf16x8 a, bf16x8 b, f32x4 c) {
    return __builtin_amdgcn_mfma_f32_16x16x32_bf16(a, b, c, 0, 0, 0);
}
// one v_cvt_pk_bf16_f32: dst = {bf16(lo) , bf16(hi)<<16}
__device__ __forceinline__ unsigned int pk2(float lo, float hi) {
    unsigned int r;
    asm("v_cvt_pk_bf16_f32 %0, %1, %2" : "=v"(r) : "v"(lo), "v"(hi));
    return r;
}
// split 8 f32 -> hi/lo bf16x8 (value == hi + lo to ~2^-16 rel; RNE both halves).
// R4/R5 lesson: single-f16 storage fails the 10-step feedback loop; the 3-term
// split product Ah*Bh + Ah*Bl + Al*Bh is f32-equivalent.
__device__ __forceinline__ void split8(const float v[8], bf16x8& hi, bf16x8& lo) {
    u32x4 H, L;
#pragma unroll
    for (int j = 0; j < 4; ++j) {
        const unsigned int h = pk2(v[2 * j], v[2 * j + 1]);
        H[j] = h;
        const float h0 = __uint_as_float(h << 16);
        const float h1 = __uint_as_float(h & 0xffff0000u);
        L[j] = pk2(v[2 * j] - h0, v[2 * j + 1] - h1);
    }
    hi = __builtin_bit_cast(bf16x8, H);
    lo = __builtin_bit_cast(bf16x8, L);
}

__device__ __forceinline__ float fast_tanh(float v) {
    float e = __expf(2.0f * v);
    return 1.0f - __fdividef(2.0f, e + 1.0f);
}
__device__ __forceinline__ float inv_norm_clamped(float n2) {
    return fminf(__builtin_amdgcn_rsqf(n2), 1.0f);
}
// butterfly sum across the 4 lanes {l, l^16, l^32, l^48} holding one column
__device__ __forceinline__ float bsum4(float x) {
    x += __shfl_xor(x, 16);
    x += __shfl_xor(x, 32);
    return x;
}

// waves_per_eu(3,3): 170-VGPR budget for ~135 live (MFMA frags + state, mostly
// non-rematerializable). R1/R6 lesson: LDS float4 weight reads at a 64-VGPR
// allocator target -> GB-scale scratch spill; here weights live in per-lane
// VGPR slices and LDS is used once (g/x transpose), scalar reads only.
__global__ __attribute__((amdgpu_waves_per_eu(3, 3))) __launch_bounds__(256)
void pdhg_kernel(
    const float* __restrict__ xg,  const float* __restrict__ Gg,  const float* __restrict__ hg,
    const float* __restrict__ W1,  const float* __restrict__ b1,
    const float* __restrict__ W2,  const float* __restrict__ b2,
    const float* __restrict__ Wmu, const float* __restrict__ bmu,
    const float* __restrict__ Wy,  const float* __restrict__ by,
    const float* __restrict__ Wp1, const float* __restrict__ bp1,
    const float* __restrict__ Wp2, const float* __restrict__ bp2,
    float* __restrict__ out, int npts)
{
    __shared__ __align__(16) float sT[256 * STRIDE];
    const int tid = threadIdx.x;

    // ============ scalar phase: encoder L1+L2, one point per thread ============
    {
        const int pt = blockIdx.x * 256 + tid;
        const int ptc = min(pt, npts - 1);     // clamp; no early return (barrier below)
        const float2 xv = reinterpret_cast<const float2*>(xg)[ptc];
        const float x0 = xv.x, x1 = xv.y;

        float g[HID];
        #pragma unroll
        for (int j = 0; j < HID; ++j) g[j] = b2[j];
        #pragma unroll
        for (int ci = 0; ci < 4; ++ci) {
            float fc[8];
            #pragma unroll
            for (int jj = 0; jj < 8; ++jj) {
                const int j = ci * 8 + jj;
                fc[jj] = fmaxf(fmaf(x0, W1[j], fmaf(x1, W1[HID + j], b1[j])), 0.0f);
            }
            #pragma unroll
            for (int ii = 0; ii < 8; ++ii) {
                const int i = ci * 8 + ii;
                #pragma unroll
                for (int j = 0; j < HID; ++j) g[j] = fmaf(fc[ii], W2[i * HID + j], g[j]);
            }
        }
        // stage x + relu(g) for the in-wave transpose; row = 144B (16B aligned)
        float* row = sT + tid * STRIDE;
        row[0] = x0; row[1] = x1;
        #pragma unroll
        for (int jq = 0; jq < 8; ++jq) {
            const int j = jq * 4;
            reinterpret_cast<float4*>(row + 4)[jq] = make_float4(
                fmaxf(g[j], 0.f), fmaxf(g[j + 1], 0.f),
                fmaxf(g[j + 2], 0.f), fmaxf(g[j + 3], 0.f));
        }
    }
    __syncthreads();

    // ============ MFMA-layout phase ============
    // Layout (m89-verified C/D): lane holds point q = colq of each tile,
    // rows e = e0..e0+3. A/B frags: non-k index = lane&15, k-slice = (lane>>4)*8+i
    // (any consistent per-lane k-bijection is product-invariant).
    const int lane = tid & 63;
    const int colq = lane & 15;
    const int kg   = lane >> 4;
    const int k0   = kg * 8;
    const int e0   = kg * 4;
    const int pbase = blockIdx.x * 256 + (tid >> 6) * 64;

    // per-lane geometry rows
    float gxr[4], gyr[4];
    f32x4 bp2c;
    {
        float s00 = 0.f, s01 = 0.f, s11 = 0.f;
        #pragma unroll
        for (int r = 0; r < 4; ++r) {
            gxr[r] = Gg[2 * (e0 + r)];
            gyr[r] = Gg[2 * (e0 + r) + 1];
            bp2c[r] = bp2[e0 + r];
            s00 = fmaf(gxr[r], gxr[r], s00);
            s01 = fmaf(gxr[r], gyr[r], s01);
            s11 = fmaf(gyr[r], gyr[r], s11);
        }
        // reduce across the 4 row-groups -> full GtG on every lane
        s00 = bsum4(s00); s01 = bsum4(s01); s11 = bsum4(s11);
        gxr[0] = gxr[0]; // keep order
        // fold TAU
        s00 *= TAU; s01 *= TAU; s11 *= TAU;
        // stash in registers via locals below
        // (assigned after this block)
        __builtin_memcpy(nullptr, nullptr, 0); // no-op
        // store into dedicated consts:
        // handled right below
        (void)s00; (void)s01; (void)s11;
        // fallthrough via variables:
        #define TG_DECL
        // declare outside to keep scope
        // (see tg00/tg01/tg11 below)
        // -- we simply recompute assignment outside --
        // NOTE: kept simple by re-deriving below
    }
    // TAU*GtG (recompute cleanly; trivial cost, wave-uniform value per lane)
    float tg00, tg01, tg11;
    {
        float s00 = 0.f, s01 = 0.f, s11 = 0.f;
        #pragma unroll
        for (int r = 0; r < 4; ++r) {
            s00 = fmaf(gxr[r], gxr[r], s00);
            s01 = fmaf(gxr[r], gyr[r], s01);
            s11 = fmaf(gyr[r], gyr[r], s11);
        }
        tg00 = TAU * bsum4(s00);
        tg01 = TAU * bsum4(s01);
        tg11 = TAU * bsum4(s11);
    }

    // constant fragments / per-lane k-slices (VGPR-resident, loaded once)
    bf16x8 wp2h, wp2l;
    {
        float w[8];
        #pragma unroll
        for (int i = 0; i < 8; ++i) w[i] = Wp2[(k0 + i) * E + colq];   // A[e=colq][k]
        split8(w, wp2h, wp2l);
    }
    float wp1a[8], wp1b[8], bp1r[8];
    #pragma unroll
    for (int i = 0; i < 8; ++i) {
        wp1a[i] = Wp1[k0 + i];
        wp1b[i] = Wp1[HID + k0 + i];
        bp1r[i] = bp1[k0 + i];
    }

    float mu[NT][4], ta[NT][4];
    float y0[NT], y1[NT], v0[NT], v1[NT], tc0[NT], tc1[NT];

    // ---------------- heads in MFMA layout ----------------
    {
        bf16x8 wmuh, wmul;
        {
            float w[8];
            #pragma unroll
            for (int i = 0; i < 8; ++i) w[i] = Wmu[(k0 + i) * E + colq];
            split8(w, wmuh, wmul);
        }
        f32x4 bmuc;
        float hr[4];
        #pragma unroll
        for (int r = 0; r < 4; ++r) { bmuc[r] = bmu[e0 + r]; hr[r] = hg[e0 + r]; }
        float wyar[8], wybr[8];
        #pragma unroll
        for (int i = 0; i < 8; ++i) {
            wyar[i] = Wy[(k0 + i) * 2];
            wybr[i] = Wy[(k0 + i) * 2 + 1];
        }
        const float by0 = by[0], by1 = by[1];

        #pragma unroll
        for (int t = 0; t < NT; ++t) {
            const float* prow = sT + (size_t)((tid >> 6) * 64 + t * 16 + colq) * STRIDE;
            const float px0 = prow[0], px1 = prow[1];
            float gf[8];
            #pragma unroll
            for (int i = 0; i < 8; ++i) gf[i] = prow[4 + k0 + i];
            // y head: per-lane k-slice partial + butterfly over k-groups
            float p0 = 0.f, p1 = 0.f;
            #pragma unroll
            for (int i = 0; i < 8; ++i) {
                p0 = fmaf(gf[i], wyar[i], p0);
                p1 = fmaf(gf[i], wybr[i], p1);
            }
            y0[t] = fast_tanh(by0 + bsum4(p0));
            y1[t] = fast_tanh(by1 + bsum4(p1));
            // mu head: 3-MFMA split chain, C = bmu rows
            bf16x8 gh, gl;
            split8(gf, gh, gl);
            f32x4 d = mfma16(wmul, gh, bmuc);
            d = mfma16(wmuh, gl, d);
            d = mfma16(wmuh, gh, d);
            float q0 = 0.f, q1 = 0.f, r0 = 0.f, r1 = 0.f;
            #pragma unroll
            for (int r = 0; r < 4; ++r) {
                const float m = fmaxf(d[r], 0.0f);
                mu[t][r] = m;
                const float tae = TAU * fmaf(px0, gxr[r], fmaf(px1, gyr[r], -hr[r]));
                ta[t][r] = tae;
                q0 = fmaf(tae, gxr[r], q0);
                q1 = fmaf(tae, gyr[r], q1);
                r0 = fmaf(m, gxr[r], r0);
                r1 = fmaf(m, gyr[r], r1);
            }
            tc0[t] = bsum4(q0); tc1[t] = bsum4(q1);
            v0[t]  = bsum4(r0); v1[t]  = bsum4(r1);
        }
    }

    // ---------------- PDHG steps ----------------
    #pragma unroll 1
    for (int s = 0; s < NSTEP; ++s) {
        #pragma unroll
        for (int t = 0; t < NT; ++t) {
            // y += SIGMA*v; unit-ball project (redundant x4 lanes, identical)
            float a0 = fmaf(SIGMA, v0[t], y0[t]);
            float a1 = fmaf(SIGMA, v1[t], y1[t]);
            const float sc = inv_norm_clamped(fmaf(a0, a0, a1 * a1));
            a0 *= sc; a1 *= sc;
            y0[t] = a0; y1[t] = a1;
            // z = v + tc - TAU*GtG@y
            const float z0 = fmaf(-tg00, a0, fmaf(-tg01, a1, v0[t] + tc0[t]));
            const float z1 = fmaf(-tg01, a0, fmaf(-tg11, a1, v1[t] + tc1[t]));
            const float yt0 = TAU * a0, yt1 = TAU * a1;
            // mu += ta - yt@G^T (own 4 rows)
            #pragma unroll
            for (int r = 0; r < 4; ++r)
                mu[t][r] = fmaf(-yt1, gyr[r], fmaf(-yt0, gxr[r], mu[t][r] + ta[t][r]));
            // hk for lane's B k-slice (z is lane-local: this lane's column point)
            float hk[8];
            #pragma unroll
            for (int i = 0; i < 8; ++i)
                hk[i] = fmaxf(fmaf(z0, wp1a[i], fmaf(z1, wp1b[i], bp1r[i])), 0.0f);
            bf16x8 bh, bl;
            split8(hk, bh, bl);
            // dl = Wp2^T @ hk via 3-MFMA split chain; C = bp2 rows
            f32x4 d = mfma16(wp2l, bh, bp2c);
            d = mfma16(wp2h, bl, d);
            d = mfma16(wp2h, bh, d);
            // mu = project(mu + RES*dl); maintain v
            float p0 = 0.f, p1 = 0.f;
            #pragma unroll
            for (int r = 0; r < 4; ++r) {
                const float m = fmaxf(fmaf(RES, d[r], mu[t][r]), 0.0f);
                mu[t][r] = m;
                p0 = fmaf(m, gxr[r], p0);
                p1 = fmaf(m, gyr[r], p1);
            }
            p0 = bsum4(p0); p1 = bsum4(p1);
            const float sp = inv_norm_clamped(fmaf(p0, p0, p1 * p1));
            #pragma unroll
            for (int r = 0; r < 4; ++r) mu[t][r] *= sp;
            v0[t] = sp * p0;
            v1[t] = sp * p1;
        }
    }

    // ---------------- store: one float4 per tile, wave covers 1KB/tile ----------
    #pragma unroll
    for (int t = 0; t < NT; ++t) {
        const int q = pbase + t * 16 + colq;
        if (q < npts)
            *reinterpret_cast<float4*>(out + (size_t)q * E + e0) =
                make_float4(mu[t][0], mu[t][1], mu[t][2], mu[t][3]);
    }
}

extern "C" void kernel_launch(void* const* d_in, const int* in_sizes, int n_in,
                              void* d_out, int out_size, void* d_ws, size_t ws_size,
                              hipStream_t stream) {
    const float* x   = (const float*)d_in[0];
    const float* G   = (const float*)d_in[1];
    const float* h   = (const float*)d_in[2];
    const float* W1  = (const float*)d_in[3];
    const float* b1  = (const float*)d_in[4];
    const float* W2  = (const float*)d_in[5];
    const float* b2  = (const float*)d_in[6];
    const float* Wmu = (const float*)d_in[7];
    const float* bmu = (const float*)d_in[8];
    const float* Wy  = (const float*)d_in[9];
    const float* by  = (const float*)d_in[10];
    const float* Wp1 = (const float*)d_in[11];
    const float* bp1 = (const float*)d_in[12];
    const float* Wp2 = (const float*)d_in[13];
    const float* bp2 = (const float*)d_in[14];

    const int npts = in_sizes[0] / 2;   // x is [N,2]
    const int block = 256;              // 256 points per block (1 pt/thread)
    const int grid = (npts + block - 1) / block;

    pdhg_kernel<<<grid, block, 0, stream>>>(x, G, h, W1, b1, W2, b2, Wmu, bmu,
                                            Wy, by, Wp1, bp1, Wp2, bp2,
                                            (float*)d_out, npts);
}

// Round 9
// 242.525 us; speedup vs baseline: 10.1268x; 1.0193x over previous
//
#include <hip/hip_runtime.h>

#define E 16
#define HID 32
#define NSTEP 10
#define TAU 0.5f
#define SIGMA 0.5f
#define RES 0.5f
#define NT 4          // 16-point column tiles per wave (64 pts/wave)
#define STRIDE 36     // LDS row stride (floats): 144B, 16B-aligned, bank-spread

typedef __attribute__((ext_vector_type(8))) short bf16x8;
typedef __attribute__((ext_vector_type(4))) float f32x4;
typedef __attribute__((ext_vector_type(4))) unsigned int u32x4;

__device__ __forceinline__ f32x4 mfma16(bf16x8 a, bf16x8 b, f32x4 c) {
    return __builtin_amdgcn_mfma_f32_16x16x32_bf16(a, b, c, 0, 0, 0);
}
// one v_cvt_pk_bf16_f32: dst = {bf16(lo) , bf16(hi)<<16}
__device__ __forceinline__ unsigned int pk2(float lo, float hi) {
    unsigned int r;
    asm("v_cvt_pk_bf16_f32 %0, %1, %2" : "=v"(r) : "v"(lo), "v"(hi));
    return r;
}
// split 8 f32 -> hi/lo bf16x8 (value == hi + lo to ~2^-16 rel; RNE both halves).
// R8 lesson: split error is SAFE inside the PDHG loop (R7: absmax 0.031,
// in-loop gain only) but FORBIDDEN upstream of it (R8: initial-state error
// sees the full ~300x loop gain -> 0.317 fail). Encoder/heads stay f32.
__device__ __forceinline__ void split8(const float v[8], bf16x8& hi, bf16x8& lo) {
    u32x4 H, L;
#pragma unroll
    for (int j = 0; j < 4; ++j) {
        const unsigned int h = pk2(v[2 * j], v[2 * j + 1]);
        H[j] = h;
        const float h0 = __uint_as_float(h << 16);
        const float h1 = __uint_as_float(h & 0xffff0000u);
        L[j] = pk2(v[2 * j] - h0, v[2 * j + 1] - h1);
    }
    hi = __builtin_bit_cast(bf16x8, H);
    lo = __builtin_bit_cast(bf16x8, L);
}

__device__ __forceinline__ float fast_tanh(float v) {
    float e = __expf(2.0f * v);
    return 1.0f - __fdividef(2.0f, e + 1.0f);
}
__device__ __forceinline__ float inv_norm_clamped(float n2) {
    return fminf(__builtin_amdgcn_rsqf(n2), 1.0f);
}
// butterfly sum across the 4 lanes {l, l^16, l^32, l^48} holding one column
__device__ __forceinline__ float bsum4(float x) {
    x += __shfl_xor(x, 16);
    x += __shfl_xor(x, 32);
    return x;
}

// waves_per_eu(3,4): single-variable change vs R7's (3,3), which self-capped
// occupancy at 31% (3 waves/SIMD) while calibrated real VALU issue ~47%
// (VALUBusy/2; gfx94x derived-formula inflation on SIMD-32) -> ~half stall.
// LDS 36KB/block caps residency at 4 blocks/CU = 4 waves/SIMD; VGPR 80 fits
// the 128 budget of 4 waves/EU. R6 spill trigger (per-lane LDS float4 weight
// reads at 64-reg target) absent here.
__global__ __attribute__((amdgpu_waves_per_eu(3, 4))) __launch_bounds__(256)
void pdhg_kernel(
    const float* __restrict__ xg,  const float* __restrict__ Gg,  const float* __restrict__ hg,
    const float* __restrict__ W1,  const float* __restrict__ b1,
    const float* __restrict__ W2,  const float* __restrict__ b2,
    const float* __restrict__ Wmu, const float* __restrict__ bmu,
    const float* __restrict__ Wy,  const float* __restrict__ by,
    const float* __restrict__ Wp1, const float* __restrict__ bp1,
    const float* __restrict__ Wp2, const float* __restrict__ bp2,
    float* __restrict__ out, int npts)
{
    __shared__ __align__(16) float sT[256 * STRIDE];
    const int tid = threadIdx.x;

    // ============ scalar phase: encoder L1+L2 (f32), one point per thread ============
    {
        const int pt = blockIdx.x * 256 + tid;
        const int ptc = min(pt, npts - 1);     // clamp; no early return (barrier below)
        const float2 xv = reinterpret_cast<const float2*>(xg)[ptc];
        const float x0 = xv.x, x1 = xv.y;

        float g[HID];
        #pragma unroll
        for (int j = 0; j < HID; ++j) g[j] = b2[j];
        #pragma unroll
        for (int ci = 0; ci < 4; ++ci) {
            float fc[8];
            #pragma unroll
            for (int jj = 0; jj < 8; ++jj) {
                const int j = ci * 8 + jj;
                fc[jj] = fmaxf(fmaf(x0, W1[j], fmaf(x1, W1[HID + j], b1[j])), 0.0f);
            }
            #pragma unroll
            for (int ii = 0; ii < 8; ++ii) {
                const int i = ci * 8 + ii;
                #pragma unroll
                for (int j = 0; j < HID; ++j) g[j] = fmaf(fc[ii], W2[i * HID + j], g[j]);
            }
        }
        // stage x + relu(g) for the in-wave transpose; row = 144B (16B aligned)
        float* row = sT + tid * STRIDE;
        row[0] = x0; row[1] = x1;
        #pragma unroll
        for (int jq = 0; jq < 8; ++jq) {
            const int j = jq * 4;
            reinterpret_cast<float4*>(row + 4)[jq] = make_float4(
                fmaxf(g[j], 0.f), fmaxf(g[j + 1], 0.f),
                fmaxf(g[j + 2], 0.f), fmaxf(g[j + 3], 0.f));
        }
    }
    __syncthreads();

    // ============ MFMA-layout phase ============
    // C/D layout (m89): col = lane&15 (point), row = (lane>>4)*4 + r.
    // A/B frags: non-k index = lane&15, k-slice = (lane>>4)*8+i (shared map:
    // product is invariant under any per-lane k-bijection used by BOTH operands).
    const int lane = tid & 63;
    const int colq = lane & 15;
    const int kg   = lane >> 4;
    const int k0   = kg * 8;
    const int e0   = kg * 4;
    const int pbase = blockIdx.x * 256 + (tid >> 6) * 64;

    // per-lane geometry rows + TAU*GtG
    float gxr[4], gyr[4];
    f32x4 bp2c;
    #pragma unroll
    for (int r = 0; r < 4; ++r) {
        gxr[r] = Gg[2 * (e0 + r)];
        gyr[r] = Gg[2 * (e0 + r) + 1];
        bp2c[r] = bp2[e0 + r];
    }
    float tg00, tg01, tg11;
    {
        float s00 = 0.f, s01 = 0.f, s11 = 0.f;
        #pragma unroll
        for (int r = 0; r < 4; ++r) {
            s00 = fmaf(gxr[r], gxr[r], s00);
            s01 = fmaf(gxr[r], gyr[r], s01);
            s11 = fmaf(gyr[r], gyr[r], s11);
        }
        tg00 = TAU * bsum4(s00);
        tg01 = TAU * bsum4(s01);
        tg11 = TAU * bsum4(s11);
    }

    // prox-loop constant fragments (VGPR-resident, loaded once)
    bf16x8 wp2h, wp2l;
    {
        float w[8];
        #pragma unroll
        for (int i = 0; i < 8; ++i) w[i] = Wp2[(k0 + i) * E + colq];   // A[e=colq][k]
        split8(w, wp2h, wp2l);
    }
    float wp1a[8], wp1b[8], bp1r[8];
    #pragma unroll
    for (int i = 0; i < 8; ++i) {
        wp1a[i] = Wp1[k0 + i];
        wp1b[i] = Wp1[HID + k0 + i];
        bp1r[i] = bp1[k0 + i];
    }

    float mu[NT][4], ta[NT][4];
    float y0[NT], y1[NT], v0[NT], v1[NT], tc0[NT], tc1[NT];

    // ---------------- heads in MFMA layout ----------------
    {
        bf16x8 wmuh, wmul;
        {
            float w[8];
            #pragma unroll
            for (int i = 0; i < 8; ++i) w[i] = Wmu[(k0 + i) * E + colq];
            split8(w, wmuh, wmul);
        }
        f32x4 bmuc;
        float hr[4];
        #pragma unroll
        for (int r = 0; r < 4; ++r) { bmuc[r] = bmu[e0 + r]; hr[r] = hg[e0 + r]; }
        float wyar[8], wybr[8];
        #pragma unroll
        for (int i = 0; i < 8; ++i) {
            wyar[i] = Wy[(k0 + i) * 2];
            wybr[i] = Wy[(k0 + i) * 2 + 1];
        }
        const float by0 = by[0], by1 = by[1];

        #pragma unroll
        for (int t = 0; t < NT; ++t) {
            const float* prow = sT + (size_t)((tid >> 6) * 64 + t * 16 + colq) * STRIDE;
            const float px0 = prow[0], px1 = prow[1];
            float gf[8];
            #pragma unroll
            for (int i = 0; i < 8; ++i) gf[i] = prow[4 + k0 + i];
            // y head: per-lane k-slice partial + butterfly over k-groups
            float p0 = 0.f, p1 = 0.f;
            #pragma unroll
            for (int i = 0; i < 8; ++i) {
                p0 = fmaf(gf[i], wyar[i], p0);
                p1 = fmaf(gf[i], wybr[i], p1);
            }
            y0[t] = fast_tanh(by0 + bsum4(p0));
            y1[t] = fast_tanh(by1 + bsum4(p1));
            // mu head: 3-MFMA split chain, C = bmu rows (in-loop-adjacent but
            // verified safe in R7: absmax 0.031)
            bf16x8 gh, gl;
            split8(gf, gh, gl);
            f32x4 d = mfma16(wmul, gh, bmuc);
            d = mfma16(wmuh, gl, d);
            d = mfma16(wmuh, gh, d);
            float q0 = 0.f, q1 = 0.f, r0 = 0.f, r1 = 0.f;
            #pragma unroll
            for (int r = 0; r < 4; ++r) {
                const float m = fmaxf(d[r], 0.0f);
                mu[t][r] = m;
                const float tae = TAU * fmaf(px0, gxr[r], fmaf(px1, gyr[r], -hr[r]));
                ta[t][r] = tae;
                q0 = fmaf(tae, gxr[r], q0);
                q1 = fmaf(tae, gyr[r], q1);
                r0 = fmaf(m, gxr[r], r0);
                r1 = fmaf(m, gyr[r], r1);
            }
            tc0[t] = bsum4(q0); tc1[t] = bsum4(q1);
            v0[t]  = bsum4(r0); v1[t]  = bsum4(r1);
        }
    }

    // ---------------- PDHG steps (identical to R7) ----------------
    #pragma unroll 1
    for (int s = 0; s < NSTEP; ++s) {
        #pragma unroll
        for (int t = 0; t < NT; ++t) {
            // y += SIGMA*v; unit-ball project (redundant x4 lanes, identical)
            float a0 = fmaf(SIGMA, v0[t], y0[t]);
            float a1 = fmaf(SIGMA, v1[t], y1[t]);
            const float sc = inv_norm_clamped(fmaf(a0, a0, a1 * a1));
            a0 *= sc; a1 *= sc;
            y0[t] = a0; y1[t] = a1;
            // z = v + tc - TAU*GtG@y
            const float z0 = fmaf(-tg00, a0, fmaf(-tg01, a1, v0[t] + tc0[t]));
            const float z1 = fmaf(-tg01, a0, fmaf(-tg11, a1, v1[t] + tc1[t]));
            const float yt0 = TAU * a0, yt1 = TAU * a1;
            // mu += ta - yt@G^T (own 4 rows)
            #pragma unroll
            for (int r = 0; r < 4; ++r)
                mu[t][r] = fmaf(-yt1, gyr[r], fmaf(-yt0, gxr[r], mu[t][r] + ta[t][r]));
            // hk for lane's B k-slice (z is lane-local: this lane's column point)
            float hk[8];
            #pragma unroll
            for (int i = 0; i < 8; ++i)
                hk[i] = fmaxf(fmaf(z0, wp1a[i], fmaf(z1, wp1b[i], bp1r[i])), 0.0f);
            bf16x8 bh, bl;
            split8(hk, bh, bl);
            // dl = Wp2^T @ hk via 3-MFMA split chain; C = bp2 rows
            f32x4 d = mfma16(wp2l, bh, bp2c);
            d = mfma16(wp2h, bl, d);
            d = mfma16(wp2h, bh, d);
            // mu = project(mu + RES*dl); maintain v
            float p0 = 0.f, p1 = 0.f;
            #pragma unroll
            for (int r = 0; r < 4; ++r) {
                const float m = fmaxf(fmaf(RES, d[r], mu[t][r]), 0.0f);
                mu[t][r] = m;
                p0 = fmaf(m, gxr[r], p0);
                p1 = fmaf(m, gyr[r], p1);
            }
            p0 = bsum4(p0); p1 = bsum4(p1);
            const float sp = inv_norm_clamped(fmaf(p0, p0, p1 * p1));
            #pragma unroll
            for (int r = 0; r < 4; ++r) mu[t][r] *= sp;
            v0[t] = sp * p0;
            v1[t] = sp * p1;
        }
    }

    // ---------------- store: one float4 per tile row-slice ----------------
    #pragma unroll
    for (int t = 0; t < NT; ++t) {
        const int q = pbase + t * 16 + colq;
        if (q < npts)
            *reinterpret_cast<float4*>(out + (size_t)q * E + e0) =
                make_float4(mu[t][0], mu[t][1], mu[t][2], mu[t][3]);
    }
}

extern "C" void kernel_launch(void* const* d_in, const int* in_sizes, int n_in,
                              void* d_out, int out_size, void* d_ws, size_t ws_size,
                              hipStream_t stream) {
    const float* x   = (const float*)d_in[0];
    const float* G   = (const float*)d_in[1];
    const float* h   = (const float*)d_in[2];
    const float* W1  = (const float*)d_in[3];
    const float* b1  = (const float*)d_in[4];
    const float* W2  = (const float*)d_in[5];
    const float* b2  = (const float*)d_in[6];
    const float* Wmu = (const float*)d_in[7];
    const float* bmu = (const float*)d_in[8];
    const float* Wy  = (const float*)d_in[9];
    const float* by  = (const float*)d_in[10];
    const float* Wp1 = (const float*)d_in[11];
    const float* bp1 = (const float*)d_in[12];
    const float* Wp2 = (const float*)d_in[13];
    const float* bp2 = (const float*)d_in[14];

    const int npts = in_sizes[0] / 2;   // x is [N,2]
    const int block = 256;              // 256 points per block (1 pt/thread)
    const int grid = (npts + block - 1) / block;

    pdhg_kernel<<<grid, block, 0, stream>>>(x, G, h, W1, b1, W2, b2, Wmu, bmu,
                                            Wy, by, Wp1, bp1, Wp2, bp2,
                                            (float*)d_out, npts);
}